// Round 1
// baseline (743.168 us; speedup 1.0000x reference)
//
#include <hip/hip_runtime.h>
#include <float.h>
#include <math.h>

#define B_ 16
#define N_ 128
#define C_ 768
#define G_ 2000
#define CK_ 100
#define ALPHA_ 0.6f
#define EPS_ 1e-12f

// ---------------- helpers ----------------
__device__ inline float wave_sum_lane0(float s) {
  #pragma unroll
  for (int off = 32; off > 0; off >>= 1) s += __shfl_down(s, off);
  return s;  // valid in lane 0
}
__device__ inline float wave_sum_all(float s) {
  #pragma unroll
  for (int off = 1; off < 64; off <<= 1) s += __shfl_xor(s, off);
  return s;
}

// ---------------- inverse norms (one wave per 768-vector) ----------------
__global__ void invnorm_kernel(const float* __restrict__ src, float* __restrict__ inv, int nvec) {
  int wid = (blockIdx.x * blockDim.x + threadIdx.x) >> 6;
  int lane = threadIdx.x & 63;
  if (wid >= nvec) return;
  const float4* v = (const float4*)(src + (size_t)wid * C_);
  float s = 0.f;
  #pragma unroll
  for (int i = 0; i < 3; ++i) {
    float4 x = v[lane + 64 * i];
    s += x.x * x.x + x.y * x.y + x.z * x.z + x.w * x.w;
  }
  s = wave_sum_lane0(s);
  if (lane == 0) inv[wid] = 1.0f / fmaxf(sqrtf(s), EPS_);
}

// ---------------- normalize query patches (one wave per vector) ----------------
__global__ void qnorm_kernel(const float* __restrict__ qp, float* __restrict__ qn) {
  int wid = (blockIdx.x * blockDim.x + threadIdx.x) >> 6;
  int lane = threadIdx.x & 63;
  if (wid >= B_ * N_) return;
  const float4* v = (const float4*)(qp + (size_t)wid * C_);
  float4* o = (float4*)(qn + (size_t)wid * C_);
  float4 x0 = v[lane], x1 = v[lane + 64], x2 = v[lane + 128];
  float s = x0.x * x0.x + x0.y * x0.y + x0.z * x0.z + x0.w * x0.w
          + x1.x * x1.x + x1.y * x1.y + x1.z * x1.z + x1.w * x1.w
          + x2.x * x2.x + x2.y * x2.y + x2.z * x2.z + x2.w * x2.w;
  s = wave_sum_all(s);
  float inv = 1.0f / fmaxf(sqrtf(s), EPS_);
  x0.x *= inv; x0.y *= inv; x0.z *= inv; x0.w *= inv;
  x1.x *= inv; x1.y *= inv; x1.z *= inv; x1.w *= inv;
  x2.x *= inv; x2.y *= inv; x2.z *= inv; x2.w *= inv;
  o[lane] = x0; o[lane + 64] = x1; o[lane + 128] = x2;
}

// ---------------- cls cosine distances: dall[b][g] ----------------
__global__ void clsdist_kernel(const float* __restrict__ gcls, const float* __restrict__ qcls,
                               const float* __restrict__ ginv, const float* __restrict__ qcinv,
                               float* __restrict__ dall) {
  int id = (blockIdx.x * blockDim.x + threadIdx.x) >> 6;
  int lane = threadIdx.x & 63;
  if (id >= B_ * G_) return;
  int b = id / G_, g = id - b * G_;
  const float4* gv = (const float4*)(gcls + (size_t)g * C_);
  const float4* qv = (const float4*)(qcls + (size_t)b * C_);
  float s = 0.f;
  #pragma unroll
  for (int i = 0; i < 3; ++i) {
    float4 x = gv[lane + 64 * i], y = qv[lane + 64 * i];
    s += x.x * y.x + x.y * y.y + x.z * y.z + x.w * y.w;
  }
  s = wave_sum_lane0(s);
  if (lane == 0) dall[id] = s * ginv[g] * qcinv[b];
}

// ---------------- top-100 per sample (iterative argmax, tie -> lower index) ----------------
__global__ void top100_kernel(const float* __restrict__ dall, int* __restrict__ cls_idx,
                              float* __restrict__ dsel) {
  __shared__ float vals[G_];
  __shared__ float wbv[4];
  __shared__ int wbi[4];
  int b = blockIdx.x, t = threadIdx.x;
  for (int i = t; i < G_; i += 256) vals[i] = dall[b * G_ + i];
  __syncthreads();
  for (int it = 0; it < CK_; ++it) {
    float bv = -FLT_MAX; int bi = 0x7fffffff;
    for (int i = t; i < G_; i += 256) {
      float vv = vals[i];
      if (vv > bv || (vv == bv && i < bi)) { bv = vv; bi = i; }
    }
    #pragma unroll
    for (int off = 1; off < 64; off <<= 1) {
      float ov = __shfl_xor(bv, off);
      int   oi = __shfl_xor(bi, off);
      if (ov > bv || (ov == bv && oi < bi)) { bv = ov; bi = oi; }
    }
    if ((t & 63) == 0) { wbv[t >> 6] = bv; wbi[t >> 6] = bi; }
    __syncthreads();
    if (t == 0) {
      #pragma unroll
      for (int w = 1; w < 4; ++w) {
        if (wbv[w] > bv || (wbv[w] == bv && wbi[w] < bi)) { bv = wbv[w]; bi = wbi[w]; }
      }
      cls_idx[b * CK_ + it] = bi;
      dsel[b * CK_ + it] = bv;
      vals[bi] = -FLT_MAX;
    }
    __syncthreads();
  }
}

// ---------------- EMD kernel: one block per (b,k); 128x128x768 fp32 GEMM + row/col max ----------------
__global__ __launch_bounds__(256, 2) void emd_kernel(
    const float* __restrict__ qn, const float* __restrict__ gpat,
    const int* __restrict__ cls_idx, const float* __restrict__ dsel,
    float* __restrict__ dist) {
  __shared__ float As[16][128];
  __shared__ float Bs[16][128];
  __shared__ float red[128][16];
  __shared__ float bss[256];
  __shared__ float binv[128];
  __shared__ float rowsum_s[1];

  int blk = blockIdx.x;
  int b = blk / CK_;
  int g = cls_idx[blk];
  const float* Aptr = qn + (size_t)b * (N_ * C_);
  const float* Bptr = gpat + (size_t)g * (N_ * C_);

  int t = threadIdx.x;
  int wv = t >> 6, lane = t & 63;
  int tn = (lane & 7) | ((wv & 1) << 3);          // 0..15
  int tm = ((lane >> 3) & 7) | ((wv >> 1) << 3);  // 0..15
  int srow = t >> 1, scol = (t & 1) << 3;

  float acc[8][8];
  #pragma unroll
  for (int i = 0; i < 8; ++i)
    #pragma unroll
    for (int j = 0; j < 8; ++j) acc[i][j] = 0.f;
  float bsq = 0.f;

  const float* Arow = Aptr + (size_t)srow * C_ + scol;
  const float* Brow = Bptr + (size_t)srow * C_ + scol;

  for (int k0 = 0; k0 < C_; k0 += 16) {
    float4 a0 = *(const float4*)(Arow + k0);
    float4 a1 = *(const float4*)(Arow + k0 + 4);
    float4 b0 = *(const float4*)(Brow + k0);
    float4 b1 = *(const float4*)(Brow + k0 + 4);
    __syncthreads();
    As[scol + 0][srow] = a0.x; As[scol + 1][srow] = a0.y;
    As[scol + 2][srow] = a0.z; As[scol + 3][srow] = a0.w;
    As[scol + 4][srow] = a1.x; As[scol + 5][srow] = a1.y;
    As[scol + 6][srow] = a1.z; As[scol + 7][srow] = a1.w;
    Bs[scol + 0][srow] = b0.x; Bs[scol + 1][srow] = b0.y;
    Bs[scol + 2][srow] = b0.z; Bs[scol + 3][srow] = b0.w;
    Bs[scol + 4][srow] = b1.x; Bs[scol + 5][srow] = b1.y;
    Bs[scol + 6][srow] = b1.z; Bs[scol + 7][srow] = b1.w;
    bsq += b0.x * b0.x + b0.y * b0.y + b0.z * b0.z + b0.w * b0.w
         + b1.x * b1.x + b1.y * b1.y + b1.z * b1.z + b1.w * b1.w;
    __syncthreads();
    #pragma unroll
    for (int kk = 0; kk < 16; ++kk) {
      float a[8], bb[8];
      *(float4*)(a)      = *(const float4*)(&As[kk][tn * 8]);
      *(float4*)(a + 4)  = *(const float4*)(&As[kk][tn * 8 + 4]);
      *(float4*)(bb)     = *(const float4*)(&Bs[kk][tm * 8]);
      *(float4*)(bb + 4) = *(const float4*)(&Bs[kk][tm * 8 + 4]);
      #pragma unroll
      for (int i = 0; i < 8; ++i)
        #pragma unroll
        for (int j = 0; j < 8; ++j)
          acc[i][j] = fmaf(a[i], bb[j], acc[i][j]);
    }
  }

  // gallery-patch inverse norms (from squared sums accumulated during staging)
  bss[t] = bsq;
  __syncthreads();
  if (t < 128) {
    float s = bss[2 * t] + bss[2 * t + 1];
    binv[t] = 1.0f / fmaxf(sqrtf(s), EPS_);
  }
  __syncthreads();

  float bnv[8];
  #pragma unroll
  for (int j = 0; j < 8; ++j) bnv[j] = binv[tm * 8 + j];

  float rmax[8], cmax[8];
  #pragma unroll
  for (int i = 0; i < 8; ++i) rmax[i] = -FLT_MAX;
  #pragma unroll
  for (int j = 0; j < 8; ++j) cmax[j] = -FLT_MAX;
  #pragma unroll
  for (int i = 0; i < 8; ++i)
    #pragma unroll
    for (int j = 0; j < 8; ++j) {
      float s = acc[i][j] * bnv[j];
      rmax[i] = fmaxf(rmax[i], s);
      cmax[j] = fmaxf(cmax[j], s);
    }

  // row phase: max over m, then mean over n
  #pragma unroll
  for (int i = 0; i < 8; ++i) red[tn * 8 + i][tm] = rmax[i];
  __syncthreads();
  float part = 0.f;
  if (t < 128) {
    float m = red[t][0];
    #pragma unroll
    for (int w = 1; w < 16; ++w) m = fmaxf(m, red[t][w]);
    part = m;
  }
  bss[t] = part;
  __syncthreads();
  for (int s = 128; s > 0; s >>= 1) {
    if (t < s) bss[t] += bss[t + s];
    __syncthreads();
  }
  if (t == 0) rowsum_s[0] = bss[0];
  __syncthreads();

  // col phase: max over n, then mean over m
  #pragma unroll
  for (int j = 0; j < 8; ++j) red[tm * 8 + j][tn] = cmax[j];
  __syncthreads();
  part = 0.f;
  if (t < 128) {
    float m = red[t][0];
    #pragma unroll
    for (int w = 1; w < 16; ++w) m = fmaxf(m, red[t][w]);
    part = m;
  }
  bss[t] = part;
  __syncthreads();
  for (int s = 128; s > 0; s >>= 1) {
    if (t < s) bss[t] += bss[t + s];
    __syncthreads();
  }
  if (t == 0) {
    float emd = 0.5f * (rowsum_s[0] + bss[0]) / 128.0f;
    dist[blk] = ALPHA_ * dsel[blk] + (1.0f - ALPHA_) * emd;
  }
}

// ---------------- final top-k + cls mean ----------------
__global__ void sel10_kernel(const float* __restrict__ dist, const int* __restrict__ cls_idx,
                             const float* __restrict__ gcls, float* __restrict__ out_cls,
                             int* __restrict__ nb, int TK) {
  int b = blockIdx.x, t = threadIdx.x;
  __shared__ float v[CK_];
  __shared__ int snb[64];
  for (int i = t; i < CK_; i += 256) v[i] = dist[b * CK_ + i];
  __syncthreads();
  if (t == 0) {
    for (int j = 0; j < TK; ++j) {
      float bv = -FLT_MAX; int bi = 0;
      for (int i = 0; i < CK_; ++i) {
        if (v[i] > bv) { bv = v[i]; bi = i; }  // strict > keeps lowest index on tie
      }
      int gg = cls_idx[b * CK_ + bi];
      snb[j] = gg;
      nb[b * TK + j] = gg;
      v[bi] = -FLT_MAX;
    }
  }
  __syncthreads();
  float invk = 1.0f / (float)TK;
  for (int c = t; c < C_; c += 256) {
    float s = 0.f;
    for (int j = 0; j < TK; ++j) s += gcls[(size_t)snb[j] * C_ + c];
    out_cls[(size_t)b * C_ + c] = s * invk;
  }
}

// ---------------- gather selected patches to output ----------------
__global__ void gather_kernel(const float* __restrict__ gpat, const int* __restrict__ nb,
                              float* __restrict__ out, int TK) {
  int i = blockIdx.x * blockDim.x + threadIdx.x;
  int per_vec = N_ * C_ / 4;       // float4s per gallery entry
  int per_b = TK * per_vec;
  int total = B_ * per_b;
  if (i >= total) return;
  int b = i / per_b;
  int r = i - b * per_b;
  int j = r / per_vec;
  int off = r - j * per_vec;
  int g = nb[b * TK + j];
  ((float4*)out)[i] = ((const float4*)gpat)[(size_t)g * per_vec + off];
}

extern "C" void kernel_launch(void* const* d_in, const int* in_sizes, int n_in,
                              void* d_out, int out_size, void* d_ws, size_t ws_size,
                              hipStream_t stream) {
  (void)in_sizes; (void)n_in; (void)ws_size;
  const float* qcls = (const float*)d_in[0];
  const float* qpat = (const float*)d_in[1];
  const float* gcls = (const float*)d_in[2];
  const float* gpat = (const float*)d_in[3];
  int TK = (out_size / B_ - C_) / (N_ * C_);  // = top_k (10)

  float* ws = (float*)d_ws;
  float* qn    = ws;                                  // B*N*C
  float* dall  = qn + (size_t)B_ * N_ * C_;           // B*G
  float* ginv  = dall + B_ * G_;                      // G
  float* qcinv = ginv + G_;                           // B (padded 16)
  float* dsel  = qcinv + 16;                          // B*CK
  float* dist  = dsel + B_ * CK_;                     // B*CK
  int* cls_idx = (int*)(dist + B_ * CK_);             // B*CK
  int* nb      = cls_idx + B_ * CK_;                  // B*TK

  hipLaunchKernelGGL(invnorm_kernel, dim3((G_ + 3) / 4), dim3(256), 0, stream, gcls, ginv, G_);
  hipLaunchKernelGGL(invnorm_kernel, dim3((B_ + 3) / 4), dim3(256), 0, stream, qcls, qcinv, B_);
  hipLaunchKernelGGL(qnorm_kernel, dim3(B_ * N_ / 4), dim3(256), 0, stream, qpat, qn);
  hipLaunchKernelGGL(clsdist_kernel, dim3(B_ * G_ / 4), dim3(256), 0, stream,
                     gcls, qcls, ginv, qcinv, dall);
  hipLaunchKernelGGL(top100_kernel, dim3(B_), dim3(256), 0, stream, dall, cls_idx, dsel);
  hipLaunchKernelGGL(emd_kernel, dim3(B_ * CK_), dim3(256), 0, stream,
                     qn, gpat, cls_idx, dsel, dist);
  float* out_cls = (float*)d_out + (size_t)B_ * TK * N_ * C_;
  hipLaunchKernelGGL(sel10_kernel, dim3(B_), dim3(256), 0, stream,
                     dist, cls_idx, gcls, out_cls, nb, TK);
  int total4 = B_ * TK * (N_ * C_ / 4);
  hipLaunchKernelGGL(gather_kernel, dim3((total4 + 255) / 256), dim3(256), 0, stream,
                     gpat, nb, (float*)d_out, TK);
}

// Round 2
// 438.113 us; speedup vs baseline: 1.6963x; 1.6963x over previous
//
#include <hip/hip_runtime.h>
#include <float.h>
#include <math.h>

#define B_ 16
#define N_ 128
#define C_ 768
#define G_ 2000
#define CK_ 100
#define ALPHA_ 0.6f
#define EPS_ 1e-12f

typedef __attribute__((ext_vector_type(8))) short bf16x8;
typedef __attribute__((ext_vector_type(16))) float f32x16;

// ---------------- helpers ----------------
__device__ inline float wave_sum_lane0(float s) {
  #pragma unroll
  for (int off = 32; off > 0; off >>= 1) s += __shfl_down(s, off);
  return s;  // valid in lane 0
}
__device__ inline float wave_sum_all(float s) {
  #pragma unroll
  for (int off = 1; off < 64; off <<= 1) s += __shfl_xor(s, off);
  return s;
}

__device__ inline unsigned short bf16_rtn(float x) {
  unsigned u = __float_as_uint(x);
  u += 0x7fffu + ((u >> 16) & 1u);
  return (unsigned short)(u >> 16);
}
__device__ inline void split2(float x, unsigned short& h, unsigned short& l) {
  h = bf16_rtn(x);
  float r = x - __uint_as_float(((unsigned)h) << 16);
  l = bf16_rtn(r);
}
// two float4 (8 consecutive K values) -> hi uint4 (8 bf16) + lo uint4
__device__ inline void split_f4x2(float4 v0, float4 v1, uint4& hi, uint4& lo) {
  unsigned short h[8], l[8];
  split2(v0.x, h[0], l[0]); split2(v0.y, h[1], l[1]);
  split2(v0.z, h[2], l[2]); split2(v0.w, h[3], l[3]);
  split2(v1.x, h[4], l[4]); split2(v1.y, h[5], l[5]);
  split2(v1.z, h[6], l[6]); split2(v1.w, h[7], l[7]);
  hi.x = (unsigned)h[0] | ((unsigned)h[1] << 16);
  hi.y = (unsigned)h[2] | ((unsigned)h[3] << 16);
  hi.z = (unsigned)h[4] | ((unsigned)h[5] << 16);
  hi.w = (unsigned)h[6] | ((unsigned)h[7] << 16);
  lo.x = (unsigned)l[0] | ((unsigned)l[1] << 16);
  lo.y = (unsigned)l[2] | ((unsigned)l[3] << 16);
  lo.z = (unsigned)l[4] | ((unsigned)l[5] << 16);
  lo.w = (unsigned)l[6] | ((unsigned)l[7] << 16);
}

// ---------------- inverse norms (one wave per 768-vector) ----------------
__global__ void invnorm_kernel(const float* __restrict__ src, float* __restrict__ inv, int nvec) {
  int wid = (blockIdx.x * blockDim.x + threadIdx.x) >> 6;
  int lane = threadIdx.x & 63;
  if (wid >= nvec) return;
  const float4* v = (const float4*)(src + (size_t)wid * C_);
  float s = 0.f;
  #pragma unroll
  for (int i = 0; i < 3; ++i) {
    float4 x = v[lane + 64 * i];
    s += x.x * x.x + x.y * x.y + x.z * x.z + x.w * x.w;
  }
  s = wave_sum_lane0(s);
  if (lane == 0) inv[wid] = 1.0f / fmaxf(sqrtf(s), EPS_);
}

// ---------------- normalize query patches (one wave per vector) ----------------
__global__ void qnorm_kernel(const float* __restrict__ qp, float* __restrict__ qn) {
  int wid = (blockIdx.x * blockDim.x + threadIdx.x) >> 6;
  int lane = threadIdx.x & 63;
  if (wid >= B_ * N_) return;
  const float4* v = (const float4*)(qp + (size_t)wid * C_);
  float4* o = (float4*)(qn + (size_t)wid * C_);
  float4 x0 = v[lane], x1 = v[lane + 64], x2 = v[lane + 128];
  float s = x0.x * x0.x + x0.y * x0.y + x0.z * x0.z + x0.w * x0.w
          + x1.x * x1.x + x1.y * x1.y + x1.z * x1.z + x1.w * x1.w
          + x2.x * x2.x + x2.y * x2.y + x2.z * x2.z + x2.w * x2.w;
  s = wave_sum_all(s);
  float inv = 1.0f / fmaxf(sqrtf(s), EPS_);
  x0.x *= inv; x0.y *= inv; x0.z *= inv; x0.w *= inv;
  x1.x *= inv; x1.y *= inv; x1.z *= inv; x1.w *= inv;
  x2.x *= inv; x2.y *= inv; x2.z *= inv; x2.w *= inv;
  o[lane] = x0; o[lane + 64] = x1; o[lane + 128] = x2;
}

// ---------------- cls cosine distances: dall[b][g] ----------------
__global__ void clsdist_kernel(const float* __restrict__ gcls, const float* __restrict__ qcls,
                               const float* __restrict__ ginv, const float* __restrict__ qcinv,
                               float* __restrict__ dall) {
  int id = (blockIdx.x * blockDim.x + threadIdx.x) >> 6;
  int lane = threadIdx.x & 63;
  if (id >= B_ * G_) return;
  int b = id / G_, g = id - b * G_;
  const float4* gv = (const float4*)(gcls + (size_t)g * C_);
  const float4* qv = (const float4*)(qcls + (size_t)b * C_);
  float s = 0.f;
  #pragma unroll
  for (int i = 0; i < 3; ++i) {
    float4 x = gv[lane + 64 * i], y = qv[lane + 64 * i];
    s += x.x * y.x + x.y * y.y + x.z * y.z + x.w * y.w;
  }
  s = wave_sum_lane0(s);
  if (lane == 0) dall[id] = s * ginv[g] * qcinv[b];
}

// ---------------- top-100 per sample (iterative argmax, tie -> lower index) ----------------
__global__ void top100_kernel(const float* __restrict__ dall, int* __restrict__ cls_idx,
                              float* __restrict__ dsel) {
  __shared__ float vals[G_];
  __shared__ float wbv[4];
  __shared__ int wbi[4];
  int b = blockIdx.x, t = threadIdx.x;
  for (int i = t; i < G_; i += 256) vals[i] = dall[b * G_ + i];
  __syncthreads();
  for (int it = 0; it < CK_; ++it) {
    float bv = -FLT_MAX; int bi = 0x7fffffff;
    for (int i = t; i < G_; i += 256) {
      float vv = vals[i];
      if (vv > bv || (vv == bv && i < bi)) { bv = vv; bi = i; }
    }
    #pragma unroll
    for (int off = 1; off < 64; off <<= 1) {
      float ov = __shfl_xor(bv, off);
      int   oi = __shfl_xor(bi, off);
      if (ov > bv || (ov == bv && oi < bi)) { bv = ov; bi = oi; }
    }
    if ((t & 63) == 0) { wbv[t >> 6] = bv; wbi[t >> 6] = bi; }
    __syncthreads();
    if (t == 0) {
      #pragma unroll
      for (int w = 1; w < 4; ++w) {
        if (wbv[w] > bv || (wbv[w] == bv && wbi[w] < bi)) { bv = wbv[w]; bi = wbi[w]; }
      }
      cls_idx[b * CK_ + it] = bi;
      dsel[b * CK_ + it] = bv;
      vals[bi] = -FLT_MAX;
    }
    __syncthreads();
  }
}

// ---------------- EMD kernel: one block per (b,k); split-bf16 MFMA GEMM + row/col max ----------
// sim[n][m] = qn[b][n] . gpat[g][m], scaled by binv[m]. 4 waves, each owns a 64x64 quadrant
// as 2x2 MFMA 32x32 tiles. fp32 = hi + lo bf16; sim = hi*hi + hi*lo + lo*hi (lo*lo ~ 2^-18, dropped).
__global__ __launch_bounds__(256, 2) void emd_kernel(
    const float* __restrict__ qn, const float* __restrict__ gpat,
    const int* __restrict__ cls_idx, const float* __restrict__ dsel,
    float* __restrict__ dist) {
  __shared__ __align__(16) unsigned short sAhi[4096], sAlo[4096], sBhi[4096], sBlo[4096];
  __shared__ float red_row[128][2];
  __shared__ float red_col[128][2];
  __shared__ float bss[256];
  __shared__ float binv[128];

  // XCD-aware swizzle: blocks sharing b land on one XCD (qn[b] stays in that XCD's L2).
  int r = blockIdx.x;
  int xc = r & 7;
  int q = r >> 3;                       // 0..199
  int b = 2 * xc + (q >= CK_ ? 1 : 0);
  int k = (q >= CK_) ? (q - CK_) : q;
  int blk = b * CK_ + k;
  int g = cls_idx[blk];

  const float* Aptr = qn + (size_t)b * (N_ * C_);
  const float* Bptr = gpat + (size_t)g * (N_ * C_);

  int t = threadIdx.x;
  int lane = t & 63, wv = t >> 6;
  int wr = wv >> 1, wc = wv & 1;
  int l31 = lane & 31, lhi = lane >> 5;

  // staging assignment: thread t -> row m_st = t>>1, K-halfslot (t&1)*16 within 32-wide K tile
  int m_st = t >> 1, half = t & 1;
  const float* aBase = Aptr + (size_t)m_st * C_ + half * 16;
  const float* bBase = Bptr + (size_t)m_st * C_ + half * 16;
  int sw_st = (m_st >> 1) & 3;                       // 16B-slot swizzle for this row
  int e0 = m_st * 32 + (((2 * half + 0) ^ sw_st) << 3);
  int e1 = m_st * 32 + (((2 * half + 1) ^ sw_st) << 3);

  f32x16 acc00, acc01, acc10, acc11;
  #pragma unroll
  for (int e = 0; e < 16; ++e) { acc00[e] = 0.f; acc01[e] = 0.f; acc10[e] = 0.f; acc11[e] = 0.f; }

  // fragment rows/cols for this wave (K-map: lane-hi selects 8-wide K half; identical for A and B
  // so any HW K-permutation cancels)
  int rA0 = 64 * wr + l31, rA1 = rA0 + 32;
  int rB0 = 64 * wc + l31, rB1 = rB0 + 32;
  int swF = (l31 >> 1) & 3;                          // (row>>1)&3 for all four rows

  float4 a0, a1, a2, a3, b0, b1, b2, b3;
  a0 = *(const float4*)(aBase + 0);  a1 = *(const float4*)(aBase + 4);
  a2 = *(const float4*)(aBase + 8);  a3 = *(const float4*)(aBase + 12);
  b0 = *(const float4*)(bBase + 0);  b1 = *(const float4*)(bBase + 4);
  b2 = *(const float4*)(bBase + 8);  b3 = *(const float4*)(bBase + 12);

  float bsq = 0.f;
  const int NT = C_ / 32;                            // 24 K-tiles
  for (int kt = 0; kt < NT; ++kt) {
    __syncthreads();                                 // previous MFMA phase done with LDS
    bsq += b0.x * b0.x + b0.y * b0.y + b0.z * b0.z + b0.w * b0.w
         + b1.x * b1.x + b1.y * b1.y + b1.z * b1.z + b1.w * b1.w
         + b2.x * b2.x + b2.y * b2.y + b2.z * b2.z + b2.w * b2.w
         + b3.x * b3.x + b3.y * b3.y + b3.z * b3.z + b3.w * b3.w;
    uint4 h, l;
    split_f4x2(a0, a1, h, l); *(uint4*)&sAhi[e0] = h; *(uint4*)&sAlo[e0] = l;
    split_f4x2(a2, a3, h, l); *(uint4*)&sAhi[e1] = h; *(uint4*)&sAlo[e1] = l;
    split_f4x2(b0, b1, h, l); *(uint4*)&sBhi[e0] = h; *(uint4*)&sBlo[e0] = l;
    split_f4x2(b2, b3, h, l); *(uint4*)&sBhi[e1] = h; *(uint4*)&sBlo[e1] = l;
    if (kt + 1 < NT) {                               // prefetch next tile (in flight during MFMA)
      const float* ap = aBase + (kt + 1) * 32;
      const float* bp = bBase + (kt + 1) * 32;
      a0 = *(const float4*)(ap + 0);  a1 = *(const float4*)(ap + 4);
      a2 = *(const float4*)(ap + 8);  a3 = *(const float4*)(ap + 12);
      b0 = *(const float4*)(bp + 0);  b1 = *(const float4*)(bp + 4);
      b2 = *(const float4*)(bp + 8);  b3 = *(const float4*)(bp + 12);
    }
    __syncthreads();                                 // LDS tile ready
    #pragma unroll
    for (int ks = 0; ks < 2; ++ks) {
      int so = (((ks * 2 + lhi) ^ swF) << 3);
      bf16x8 ah0 = *(const bf16x8*)&sAhi[rA0 * 32 + so];
      bf16x8 al0 = *(const bf16x8*)&sAlo[rA0 * 32 + so];
      bf16x8 ah1 = *(const bf16x8*)&sAhi[rA1 * 32 + so];
      bf16x8 al1 = *(const bf16x8*)&sAlo[rA1 * 32 + so];
      bf16x8 bh0 = *(const bf16x8*)&sBhi[rB0 * 32 + so];
      bf16x8 bl0 = *(const bf16x8*)&sBlo[rB0 * 32 + so];
      bf16x8 bh1 = *(const bf16x8*)&sBhi[rB1 * 32 + so];
      bf16x8 bl1 = *(const bf16x8*)&sBlo[rB1 * 32 + so];
      acc00 = __builtin_amdgcn_mfma_f32_32x32x16_bf16(ah0, bh0, acc00, 0, 0, 0);
      acc00 = __builtin_amdgcn_mfma_f32_32x32x16_bf16(ah0, bl0, acc00, 0, 0, 0);
      acc00 = __builtin_amdgcn_mfma_f32_32x32x16_bf16(al0, bh0, acc00, 0, 0, 0);
      acc01 = __builtin_amdgcn_mfma_f32_32x32x16_bf16(ah0, bh1, acc01, 0, 0, 0);
      acc01 = __builtin_amdgcn_mfma_f32_32x32x16_bf16(ah0, bl1, acc01, 0, 0, 0);
      acc01 = __builtin_amdgcn_mfma_f32_32x32x16_bf16(al0, bh1, acc01, 0, 0, 0);
      acc10 = __builtin_amdgcn_mfma_f32_32x32x16_bf16(ah1, bh0, acc10, 0, 0, 0);
      acc10 = __builtin_amdgcn_mfma_f32_32x32x16_bf16(ah1, bl0, acc10, 0, 0, 0);
      acc10 = __builtin_amdgcn_mfma_f32_32x32x16_bf16(al1, bh0, acc10, 0, 0, 0);
      acc11 = __builtin_amdgcn_mfma_f32_32x32x16_bf16(ah1, bh1, acc11, 0, 0, 0);
      acc11 = __builtin_amdgcn_mfma_f32_32x32x16_bf16(ah1, bl1, acc11, 0, 0, 0);
      acc11 = __builtin_amdgcn_mfma_f32_32x32x16_bf16(al1, bh1, acc11, 0, 0, 0);
    }
  }

  // gallery patch inverse norms
  bss[t] = bsq;
  __syncthreads();
  if (t < 128) {
    float s = bss[2 * t] + bss[2 * t + 1];
    binv[t] = 1.0f / fmaxf(sqrtf(s), EPS_);
  }
  __syncthreads();
  float bi0 = binv[64 * wc + l31];
  float bi1 = binv[64 * wc + 32 + l31];

  // ---- row phase: per row n, max over cols m (scaled), reduce over lanes 0..31 ----
  {
    float rm[16];
    #pragma unroll
    for (int e = 0; e < 16; ++e) rm[e] = fmaxf(acc00[e] * bi0, acc01[e] * bi1);
    #pragma unroll
    for (int msk = 1; msk <= 16; msk <<= 1)
      #pragma unroll
      for (int e = 0; e < 16; ++e) rm[e] = fmaxf(rm[e], __shfl_xor(rm[e], msk));
    if (l31 == 0) {
      #pragma unroll
      for (int e = 0; e < 16; ++e)
        red_row[64 * wr + (e & 3) + 8 * (e >> 2) + 4 * lhi][wc] = rm[e];
    }
  }
  {
    float rm[16];
    #pragma unroll
    for (int e = 0; e < 16; ++e) rm[e] = fmaxf(acc10[e] * bi0, acc11[e] * bi1);
    #pragma unroll
    for (int msk = 1; msk <= 16; msk <<= 1)
      #pragma unroll
      for (int e = 0; e < 16; ++e) rm[e] = fmaxf(rm[e], __shfl_xor(rm[e], msk));
    if (l31 == 0) {
      #pragma unroll
      for (int e = 0; e < 16; ++e)
        red_row[64 * wr + 32 + (e & 3) + 8 * (e >> 2) + 4 * lhi][wc] = rm[e];
    }
  }
  // ---- col phase: per col m, max over rows n; scale by binv[m] after the max ----
  {
    float cm0 = -FLT_MAX, cm1 = -FLT_MAX;
    #pragma unroll
    for (int e = 0; e < 16; ++e) {
      cm0 = fmaxf(cm0, fmaxf(acc00[e], acc10[e]));
      cm1 = fmaxf(cm1, fmaxf(acc01[e], acc11[e]));
    }
    cm0 = fmaxf(cm0, __shfl_xor(cm0, 32)) * bi0;
    cm1 = fmaxf(cm1, __shfl_xor(cm1, 32)) * bi1;
    if (lane < 32) {
      red_col[64 * wc + lane][wr] = cm0;
      red_col[64 * wc + 32 + lane][wr] = cm1;
    }
  }
  __syncthreads();
  if (t < 128)
    bss[t] = fmaxf(red_row[t][0], red_row[t][1]) + fmaxf(red_col[t][0], red_col[t][1]);
  __syncthreads();
  if (t < 64) {
    float v = bss[t] + bss[t + 64];
    #pragma unroll
    for (int off = 32; off > 0; off >>= 1) v += __shfl_down(v, off);
    if (t == 0) {
      float emd = 0.5f * v * (1.0f / 128.0f);
      dist[blk] = ALPHA_ * dsel[blk] + (1.0f - ALPHA_) * emd;
    }
  }
}

// ---------------- final top-k + cls mean ----------------
__global__ void sel10_kernel(const float* __restrict__ dist, const int* __restrict__ cls_idx,
                             const float* __restrict__ gcls, float* __restrict__ out_cls,
                             int* __restrict__ nb, int TK) {
  int b = blockIdx.x, t = threadIdx.x;
  __shared__ float v[CK_];
  __shared__ int snb[64];
  for (int i = t; i < CK_; i += 256) v[i] = dist[b * CK_ + i];
  __syncthreads();
  if (t == 0) {
    for (int j = 0; j < TK; ++j) {
      float bv = -FLT_MAX; int bi = 0;
      for (int i = 0; i < CK_; ++i) {
        if (v[i] > bv) { bv = v[i]; bi = i; }  // strict > keeps lowest index on tie
      }
      int gg = cls_idx[b * CK_ + bi];
      snb[j] = gg;
      nb[b * TK + j] = gg;
      v[bi] = -FLT_MAX;
    }
  }
  __syncthreads();
  float invk = 1.0f / (float)TK;
  for (int c = t; c < C_; c += 256) {
    float s = 0.f;
    for (int j = 0; j < TK; ++j) s += gcls[(size_t)snb[j] * C_ + c];
    out_cls[(size_t)b * C_ + c] = s * invk;
  }
}

// ---------------- gather selected patches to output ----------------
__global__ void gather_kernel(const float* __restrict__ gpat, const int* __restrict__ nb,
                              float* __restrict__ out, int TK) {
  int i = blockIdx.x * blockDim.x + threadIdx.x;
  int per_vec = N_ * C_ / 4;       // float4s per gallery entry
  int per_b = TK * per_vec;
  int total = B_ * per_b;
  if (i >= total) return;
  int b = i / per_b;
  int r = i - b * per_b;
  int j = r / per_vec;
  int off = r - j * per_vec;
  int g = nb[b * TK + j];
  ((float4*)out)[i] = ((const float4*)gpat)[(size_t)g * per_vec + off];
}

extern "C" void kernel_launch(void* const* d_in, const int* in_sizes, int n_in,
                              void* d_out, int out_size, void* d_ws, size_t ws_size,
                              hipStream_t stream) {
  (void)in_sizes; (void)n_in; (void)ws_size;
  const float* qcls = (const float*)d_in[0];
  const float* qpat = (const float*)d_in[1];
  const float* gcls = (const float*)d_in[2];
  const float* gpat = (const float*)d_in[3];
  int TK = (out_size / B_ - C_) / (N_ * C_);  // = top_k (10)

  float* ws = (float*)d_ws;
  float* qn    = ws;                                  // B*N*C
  float* dall  = qn + (size_t)B_ * N_ * C_;           // B*G
  float* ginv  = dall + B_ * G_;                      // G
  float* qcinv = ginv + G_;                           // B (padded 16)
  float* dsel  = qcinv + 16;                          // B*CK
  float* dist  = dsel + B_ * CK_;                     // B*CK
  int* cls_idx = (int*)(dist + B_ * CK_);             // B*CK
  int* nb      = cls_idx + B_ * CK_;                  // B*TK

  hipLaunchKernelGGL(invnorm_kernel, dim3((G_ + 3) / 4), dim3(256), 0, stream, gcls, ginv, G_);
  hipLaunchKernelGGL(invnorm_kernel, dim3((B_ + 3) / 4), dim3(256), 0, stream, qcls, qcinv, B_);
  hipLaunchKernelGGL(qnorm_kernel, dim3(B_ * N_ / 4), dim3(256), 0, stream, qpat, qn);
  hipLaunchKernelGGL(clsdist_kernel, dim3(B_ * G_ / 4), dim3(256), 0, stream,
                     gcls, qcls, ginv, qcinv, dall);
  hipLaunchKernelGGL(top100_kernel, dim3(B_), dim3(256), 0, stream, dall, cls_idx, dsel);
  hipLaunchKernelGGL(emd_kernel, dim3(B_ * CK_), dim3(256), 0, stream,
                     qn, gpat, cls_idx, dsel, dist);
  float* out_cls = (float*)d_out + (size_t)B_ * TK * N_ * C_;
  hipLaunchKernelGGL(sel10_kernel, dim3(B_), dim3(256), 0, stream,
                     dist, cls_idx, gcls, out_cls, nb, TK);
  int total4 = B_ * TK * (N_ * C_ / 4);
  hipLaunchKernelGGL(gather_kernel, dim3((total4 + 255) / 256), dim3(256), 0, stream,
                     gpat, nb, (float*)d_out, TK);
}